// Round 2
// baseline (610.683 us; speedup 1.0000x reference)
//
#include <hip/hip_runtime.h>
#include <hip/hip_bf16.h>

#define NN 50000
#define EE 640000
#define FF 128
#define HH 128

typedef unsigned short ushort_t;
using f32x4  = __attribute__((ext_vector_type(4))) float;
using bf16x8 = __attribute__((ext_vector_type(8))) __bf16;
using u16x8  = __attribute__((ext_vector_type(8))) unsigned short;

__device__ __forceinline__ ushort_t f2bf(float f) {
    union { float f; unsigned int i; } v; v.f = f;
    unsigned int r = v.i + 0x7fffu + ((v.i >> 16) & 1u);
    return (ushort_t)(r >> 16);
}
__device__ __forceinline__ float fsilu(float x) { return x / (1.f + __expf(-x)); }
__device__ __forceinline__ float fsig(float x)  { return 1.f / (1.f + __expf(-x)); }

__device__ __forceinline__ u16x8 cvt8(const float* p) {
    float4 a0 = *reinterpret_cast<const float4*>(p);
    float4 a1 = *reinterpret_cast<const float4*>(p + 4);
    u16x8 v;
    v[0] = f2bf(a0.x); v[1] = f2bf(a0.y); v[2] = f2bf(a0.z); v[3] = f2bf(a0.w);
    v[4] = f2bf(a1.x); v[5] = f2bf(a1.y); v[6] = f2bf(a1.z); v[7] = f2bf(a1.w);
    return v;
}

// ---------------------------------------------------------------------------
// Edge kernel: per 16-edge tile, compute m = phi_e(h[row], h[col], d2, ea),
// write m to d_out, scatter-add m into agg[row], trans into agg_t[row], cnt.
// Wave w owns output columns [32w, 32w+32). eW1/eW2 B-fragments in registers.
// ---------------------------------------------------------------------------
__global__ __launch_bounds__(256, 2) void egcl_edge_kernel(
    const float* __restrict__ h, const float* __restrict__ pos,
    const int* __restrict__ eidx, const float* __restrict__ eattr,
    const float* __restrict__ w1, const float* __restrict__ b1,
    const float* __restrict__ w2, const float* __restrict__ b2,
    const float* __restrict__ aW, const float* __restrict__ ab,
    const float* __restrict__ pW2,
    float* __restrict__ m_out,
    float* __restrict__ agg, float* __restrict__ agg_t, float* __restrict__ cnt)
{
    // A tile: 16 edges x 296 bf16 (288 used, k>=265 zero-padded)
    __shared__ __align__(16) ushort_t A_sh[16 * 296];
    __shared__ __align__(16) ushort_t M1_sh[16 * 136];
    __shared__ float PD_sh[16][3];
    __shared__ int   ROW_sh[16];
    __shared__ float RED_sh[2][16][4];
    __shared__ float GATE_sh[16];

    const int tid  = threadIdx.x;
    const int lane = tid & 63;
    const int w    = tid >> 6;     // wave 0..3
    const int l15  = lane & 15;
    const int lg   = lane >> 4;    // 0..3

    // ---- preload weights into registers (per wave: cols 32w..32w+31) ----
    bf16x8 B1[9][2];
    bf16x8 B2[4][2];
    float b1c[2], b2c[2], aWc[2], pWc[2];
    const float abv = ab[0];
#pragma unroll
    for (int nt = 0; nt < 2; ++nt) {
        const int colg = 32 * w + 16 * nt + l15;
        b1c[nt] = b1[colg];
        b2c[nt] = b2[colg];
        aWc[nt] = aW[colg];
        pWc[nt] = pW2[colg];
#pragma unroll
        for (int ks = 0; ks < 9; ++ks) {
            u16x8 v;
#pragma unroll
            for (int j = 0; j < 8; ++j) {
                const int k = 32 * ks + 8 * lg + j;
                v[j] = (k < 265) ? f2bf(w1[k * 128 + colg]) : (ushort_t)0;
            }
            B1[ks][nt] = __builtin_bit_cast(bf16x8, v);
        }
#pragma unroll
        for (int ks = 0; ks < 4; ++ks) {
            u16x8 v;
#pragma unroll
            for (int j = 0; j < 8; ++j) {
                const int k = 32 * ks + 8 * lg + j;
                v[j] = f2bf(w2[k * 128 + colg]);
            }
            B2[ks][nt] = __builtin_bit_cast(bf16x8, v);
        }
    }

    const int ei = tid >> 4;   // edge slot 0..15 (staging)
    const int et = tid & 15;   // 16 threads per edge (staging)

    for (int tile = blockIdx.x; tile < EE / 16; tile += gridDim.x) {
        __syncthreads();   // protect LDS from previous iteration's readers

        // ---- stage e_in tile (f32 -> bf16) ----
        {
            const int e = tile * 16 + ei;
            const int r = eidx[e];
            const int c = eidx[EE + e];
            u16x8 hv = cvt8(h + (size_t)r * 128 + et * 8);
            *reinterpret_cast<u16x8*>(&A_sh[ei * 296 + et * 8]) = hv;
            u16x8 hc = cvt8(h + (size_t)c * 128 + et * 8);
            *reinterpret_cast<u16x8*>(&A_sh[ei * 296 + 128 + et * 8]) = hc;
            if (et == 0) {
                ROW_sh[ei] = r;
                const float dx = pos[r * 3 + 0] - pos[c * 3 + 0];
                const float dy = pos[r * 3 + 1] - pos[c * 3 + 1];
                const float dz = pos[r * 3 + 2] - pos[c * 3 + 2];
                PD_sh[ei][0] = dx; PD_sh[ei][1] = dy; PD_sh[ei][2] = dz;
                const float ds = dx * dx + dy * dy + dz * dz;
                u16x8 v;
                v[0] = f2bf(ds);
#pragma unroll
                for (int j = 0; j < 7; ++j) v[1 + j] = f2bf(eattr[e * 8 + j]);
                *reinterpret_cast<u16x8*>(&A_sh[ei * 296 + 256]) = v;
            } else if (et == 1) {
                u16x8 v = {0, 0, 0, 0, 0, 0, 0, 0};
                v[0] = f2bf(eattr[e * 8 + 7]);
                *reinterpret_cast<u16x8*>(&A_sh[ei * 296 + 264]) = v;
            } else if (et <= 4) {
                u16x8 z = {0, 0, 0, 0, 0, 0, 0, 0};
                *reinterpret_cast<u16x8*>(&A_sh[ei * 296 + 256 + et * 8]) = z;
            }
        }
        __syncthreads();

        // ---- layer 1: (16 x 288) @ (288 x 32-per-wave) ----
        f32x4 acc10 = {0.f, 0.f, 0.f, 0.f};
        f32x4 acc11 = {0.f, 0.f, 0.f, 0.f};
#pragma unroll
        for (int ks = 0; ks < 9; ++ks) {
            bf16x8 a = *reinterpret_cast<const bf16x8*>(&A_sh[l15 * 296 + ks * 32 + lg * 8]);
            acc10 = __builtin_amdgcn_mfma_f32_16x16x32_bf16(a, B1[ks][0], acc10, 0, 0, 0);
            acc11 = __builtin_amdgcn_mfma_f32_16x16x32_bf16(a, B1[ks][1], acc11, 0, 0, 0);
        }
#pragma unroll
        for (int nt = 0; nt < 2; ++nt) {
#pragma unroll
            for (int r = 0; r < 4; ++r) {
                const float x = (nt == 0 ? acc10[r] : acc11[r]) + b1c[nt];
                const int edge = 4 * lg + r;
                const int colg = 32 * w + 16 * nt + l15;
                M1_sh[edge * 136 + colg] = f2bf(fsilu(x));
            }
        }
        __syncthreads();

        // ---- layer 2: (16 x 128) @ (128 x 32-per-wave) ----
        f32x4 acc20 = {0.f, 0.f, 0.f, 0.f};
        f32x4 acc21 = {0.f, 0.f, 0.f, 0.f};
#pragma unroll
        for (int ks = 0; ks < 4; ++ks) {
            bf16x8 a = *reinterpret_cast<const bf16x8*>(&M1_sh[l15 * 136 + ks * 32 + lg * 8]);
            acc20 = __builtin_amdgcn_mfma_f32_16x16x32_bf16(a, B2[ks][0], acc20, 0, 0, 0);
            acc21 = __builtin_amdgcn_mfma_f32_16x16x32_bf16(a, B2[ks][1], acc21, 0, 0, 0);
        }

        float m2v[2][4];
        float pa[4] = {0.f, 0.f, 0.f, 0.f};
        float pp[4] = {0.f, 0.f, 0.f, 0.f};
#pragma unroll
        for (int nt = 0; nt < 2; ++nt) {
#pragma unroll
            for (int r = 0; r < 4; ++r) {
                const float x = (nt == 0 ? acc20[r] : acc21[r]) + b2c[nt];
                const float s = fsilu(x);
                m2v[nt][r] = s;
                pa[r] += s * aWc[nt];
                pp[r] += s * pWc[nt];
            }
        }
        // reduce across the 16 lanes holding different columns
#pragma unroll
        for (int mk = 1; mk < 16; mk <<= 1) {
#pragma unroll
            for (int r = 0; r < 4; ++r) {
                pa[r] += __shfl_xor(pa[r], mk);
                pp[r] += __shfl_xor(pp[r], mk);
            }
        }
        if (l15 == 0) {
#pragma unroll
            for (int r = 0; r < 4; ++r) {
                RED_sh[0][4 * lg + r][w] = pa[r];
                RED_sh[1][4 * lg + r][w] = pp[r];
            }
        }
        __syncthreads();

        if (tid < 16) {
            const float sa = RED_sh[0][tid][0] + RED_sh[0][tid][1] +
                             RED_sh[0][tid][2] + RED_sh[0][tid][3] + abv;
            const float sp = RED_sh[1][tid][0] + RED_sh[1][tid][1] +
                             RED_sh[1][tid][2] + RED_sh[1][tid][3];
            const float g = fsig(sa);
            const float t = g * sp;
            GATE_sh[tid] = g;
            const int r = ROW_sh[tid];
            atomicAdd(&agg_t[r * 3 + 0], PD_sh[tid][0] * t);
            atomicAdd(&agg_t[r * 3 + 1], PD_sh[tid][1] * t);
            atomicAdd(&agg_t[r * 3 + 2], PD_sh[tid][2] * t);
            atomicAdd(&cnt[r], 1.0f);
        }
        __syncthreads();

        // ---- final m write + agg scatter ----
#pragma unroll
        for (int nt = 0; nt < 2; ++nt) {
#pragma unroll
            for (int r = 0; r < 4; ++r) {
                const int edge = 4 * lg + r;
                const int colg = 32 * w + 16 * nt + l15;
                const float mf = m2v[nt][r] * GATE_sh[edge];
                const size_t e = (size_t)(tile * 16 + edge);
                m_out[e * 128 + colg] = mf;
                atomicAdd(&agg[(size_t)ROW_sh[edge] * 128 + colg], mf);
            }
        }
    }
}

// ---------------------------------------------------------------------------
// Node kernel: h_new = silu([h | agg] @ nW1 + nb1) @ nW2 + nb2 + h
// ---------------------------------------------------------------------------
__global__ __launch_bounds__(256, 2) void egcl_node_kernel(
    const float* __restrict__ h, const float* __restrict__ agg,
    const float* __restrict__ w1, const float* __restrict__ b1,
    const float* __restrict__ w2, const float* __restrict__ b2,
    float* __restrict__ hn_out)
{
    __shared__ __align__(16) ushort_t A_sh[16 * 264];   // 16 nodes x 256 (pad 264)
    __shared__ __align__(16) ushort_t M1_sh[16 * 136];

    const int tid  = threadIdx.x;
    const int lane = tid & 63;
    const int w    = tid >> 6;
    const int l15  = lane & 15;
    const int lg   = lane >> 4;

    bf16x8 B1[8][2];
    bf16x8 B2[4][2];
    float b1c[2], b2c[2];
#pragma unroll
    for (int nt = 0; nt < 2; ++nt) {
        const int colg = 32 * w + 16 * nt + l15;
        b1c[nt] = b1[colg];
        b2c[nt] = b2[colg];
#pragma unroll
        for (int ks = 0; ks < 8; ++ks) {
            u16x8 v;
#pragma unroll
            for (int j = 0; j < 8; ++j) {
                const int k = 32 * ks + 8 * lg + j;
                v[j] = f2bf(w1[k * 128 + colg]);
            }
            B1[ks][nt] = __builtin_bit_cast(bf16x8, v);
        }
#pragma unroll
        for (int ks = 0; ks < 4; ++ks) {
            u16x8 v;
#pragma unroll
            for (int j = 0; j < 8; ++j) {
                const int k = 32 * ks + 8 * lg + j;
                v[j] = f2bf(w2[k * 128 + colg]);
            }
            B2[ks][nt] = __builtin_bit_cast(bf16x8, v);
        }
    }

    const int ni = tid >> 4;
    const int nt16 = tid & 15;

    for (int tile = blockIdx.x; tile < NN / 16; tile += gridDim.x) {
        __syncthreads();
        // stage [h | bf16(agg)]
        {
            const size_t n = (size_t)tile * 16 + ni;
            u16x8 hv = cvt8(h + n * 128 + nt16 * 8);
            *reinterpret_cast<u16x8*>(&A_sh[ni * 264 + nt16 * 8]) = hv;
            u16x8 av = cvt8(agg + n * 128 + nt16 * 8);
            *reinterpret_cast<u16x8*>(&A_sh[ni * 264 + 128 + nt16 * 8]) = av;
        }
        __syncthreads();

        f32x4 acc10 = {0.f, 0.f, 0.f, 0.f};
        f32x4 acc11 = {0.f, 0.f, 0.f, 0.f};
#pragma unroll
        for (int ks = 0; ks < 8; ++ks) {
            bf16x8 a = *reinterpret_cast<const bf16x8*>(&A_sh[l15 * 264 + ks * 32 + lg * 8]);
            acc10 = __builtin_amdgcn_mfma_f32_16x16x32_bf16(a, B1[ks][0], acc10, 0, 0, 0);
            acc11 = __builtin_amdgcn_mfma_f32_16x16x32_bf16(a, B1[ks][1], acc11, 0, 0, 0);
        }
#pragma unroll
        for (int nt = 0; nt < 2; ++nt) {
#pragma unroll
            for (int r = 0; r < 4; ++r) {
                const float x = (nt == 0 ? acc10[r] : acc11[r]) + b1c[nt];
                const int nl = 4 * lg + r;
                const int colg = 32 * w + 16 * nt + l15;
                M1_sh[nl * 136 + colg] = f2bf(fsilu(x));
            }
        }
        __syncthreads();

        f32x4 acc20 = {0.f, 0.f, 0.f, 0.f};
        f32x4 acc21 = {0.f, 0.f, 0.f, 0.f};
#pragma unroll
        for (int ks = 0; ks < 4; ++ks) {
            bf16x8 a = *reinterpret_cast<const bf16x8*>(&M1_sh[l15 * 136 + ks * 32 + lg * 8]);
            acc20 = __builtin_amdgcn_mfma_f32_16x16x32_bf16(a, B2[ks][0], acc20, 0, 0, 0);
            acc21 = __builtin_amdgcn_mfma_f32_16x16x32_bf16(a, B2[ks][1], acc21, 0, 0, 0);
        }
#pragma unroll
        for (int nt = 0; nt < 2; ++nt) {
#pragma unroll
            for (int r = 0; r < 4; ++r) {
                const int nl = 4 * lg + r;
                const int colg = 32 * w + 16 * nt + l15;
                const size_t n = (size_t)tile * 16 + nl;
                const float hres = h[n * 128 + colg];   // f32 residual (L2-hot)
                const float y = (nt == 0 ? acc20[r] : acc21[r]) + b2c[nt] + hres;
                hn_out[n * 128 + colg] = y;
            }
        }
    }
}

// ---------------------------------------------------------------------------
// Pos kernel: pos_new = pos + agg_t / max(cnt, 1)
// ---------------------------------------------------------------------------
__global__ void egcl_pos_kernel(const float* __restrict__ pos,
                               const float* __restrict__ agg_t,
                               const float* __restrict__ cnt,
                               float* __restrict__ pos_out)
{
    const int n = blockIdx.x * 256 + threadIdx.x;
    if (n < NN) {
        const float c = fmaxf(cnt[n], 1.0f);
#pragma unroll
        for (int d = 0; d < 3; ++d) {
            pos_out[n * 3 + d] = pos[n * 3 + d] + agg_t[n * 3 + d] / c;
        }
    }
}

extern "C" void kernel_launch(void* const* d_in, const int* in_sizes, int n_in,
                              void* d_out, int out_size, void* d_ws, size_t ws_size,
                              hipStream_t stream)
{
    const float* h     = (const float*)d_in[0];
    const float* pos   = (const float*)d_in[1];
    const int*   eidx  = (const int*)d_in[2];
    const float* eattr = (const float*)d_in[3];
    const float* eW1   = (const float*)d_in[4];
    const float* eb1   = (const float*)d_in[5];
    const float* eW2   = (const float*)d_in[6];
    const float* eb2   = (const float*)d_in[7];
    const float* aW    = (const float*)d_in[8];
    const float* ab    = (const float*)d_in[9];
    const float* nW1   = (const float*)d_in[10];
    const float* nb1   = (const float*)d_in[11];
    const float* nW2   = (const float*)d_in[12];
    const float* nb2   = (const float*)d_in[13];
    const float* pW2   = (const float*)d_in[14];

    float* out    = (float*)d_out;
    float* hn_out = out;                                   // N*128
    float* po_out = out + (size_t)NN * 128;                // N*3
    float* m_out  = po_out + (size_t)NN * 3;               // E*128

    float* agg   = (float*)d_ws;                           // N*128 f32
    float* agg_t = agg + (size_t)NN * 128;                 // N*3
    float* cnt   = agg_t + (size_t)NN * 3;                 // N

    const size_t zbytes = sizeof(float) * (size_t)NN * (128 + 3 + 1);
    hipMemsetAsync(d_ws, 0, zbytes, stream);

    egcl_edge_kernel<<<512, 256, 0, stream>>>(h, pos, eidx, eattr,
                                              eW1, eb1, eW2, eb2, aW, ab, pW2,
                                              m_out, agg, agg_t, cnt);
    egcl_node_kernel<<<512, 256, 0, stream>>>(h, agg, nW1, nb1, nW2, nb2, hn_out);
    egcl_pos_kernel<<<(NN + 255) / 256, 256, 0, stream>>>(pos, agg_t, cnt, po_out);
}

// Round 3
// 552.839 us; speedup vs baseline: 1.1046x; 1.1046x over previous
//
#include <hip/hip_runtime.h>
#include <hip/hip_bf16.h>

#define NN 50000
#define EE 640000
#define FF 128
#define HH 128

typedef unsigned short ushort_t;
using f32x4  = __attribute__((ext_vector_type(4))) float;
using bf16x8 = __attribute__((ext_vector_type(8))) __bf16;
using u16x8  = __attribute__((ext_vector_type(8))) unsigned short;

__device__ __forceinline__ ushort_t f2bf(float f) {
    union { float f; unsigned int i; } v; v.f = f;
    unsigned int r = v.i + 0x7fffu + ((v.i >> 16) & 1u);
    return (ushort_t)(r >> 16);
}
__device__ __forceinline__ float fsilu(float x) { return x / (1.f + __expf(-x)); }
__device__ __forceinline__ float fsig(float x)  { return 1.f / (1.f + __expf(-x)); }

__device__ __forceinline__ u16x8 cvt8(const float* p) {
    float4 a0 = *reinterpret_cast<const float4*>(p);
    float4 a1 = *reinterpret_cast<const float4*>(p + 4);
    u16x8 v;
    v[0] = f2bf(a0.x); v[1] = f2bf(a0.y); v[2] = f2bf(a0.z); v[3] = f2bf(a0.w);
    v[4] = f2bf(a1.x); v[5] = f2bf(a1.y); v[6] = f2bf(a1.z); v[7] = f2bf(a1.w);
    return v;
}

// ---------------------------------------------------------------------------
// Edge kernel, 64-edge tiles. 4 waves; wave w owns output cols [32w,32w+32).
// Gate (sigmoid attention + pos dot) computed via MFMA against [aW|pW2|0..].
// ---------------------------------------------------------------------------
__global__ __launch_bounds__(256, 2) void egcl_edge_kernel(
    const float* __restrict__ h, const float* __restrict__ pos,
    const int* __restrict__ eidx, const float* __restrict__ eattr,
    const float* __restrict__ w1, const float* __restrict__ b1,
    const float* __restrict__ w2, const float* __restrict__ b2,
    const float* __restrict__ aW, const float* __restrict__ ab,
    const float* __restrict__ pW2,
    float* __restrict__ m_out,
    float* __restrict__ agg, float* __restrict__ agg_t, float* __restrict__ cnt)
{
    // A tile: 64 edges x 296 bf16 (288 used, k>=265 zero-padded).
    // After layer1, the A region is dead -> reused for M2 (64 x 136 bf16).
    __shared__ __align__(16) ushort_t A_sh[64 * 296];
    __shared__ __align__(16) ushort_t M1_sh[64 * 136];
    __shared__ float PD_sh[64][3];
    __shared__ int   ROW_sh[64];
    __shared__ float GATE_sh[64];

    ushort_t* M2_sh = A_sh;   // alias, layout [64][136]

    const int tid  = threadIdx.x;
    const int lane = tid & 63;
    const int w    = tid >> 6;     // wave 0..3
    const int l15  = lane & 15;
    const int lg   = lane >> 4;    // 0..3

    // ---- preload weights into registers (per wave: cols 32w..32w+31) ----
    bf16x8 B1[9][2];
    bf16x8 B2[4][2];
    bf16x8 Bg[4];                  // gate B: col0=aW, col1=pW2, else 0
    float b1c[2], b2c[2];
    const float abv = ab[0];
#pragma unroll
    for (int nt = 0; nt < 2; ++nt) {
        const int colg = 32 * w + 16 * nt + l15;
        b1c[nt] = b1[colg];
        b2c[nt] = b2[colg];
#pragma unroll
        for (int ks = 0; ks < 9; ++ks) {
            u16x8 v;
#pragma unroll
            for (int j = 0; j < 8; ++j) {
                const int k = 32 * ks + 8 * lg + j;
                v[j] = (k < 265) ? f2bf(w1[k * 128 + colg]) : (ushort_t)0;
            }
            B1[ks][nt] = __builtin_bit_cast(bf16x8, v);
        }
#pragma unroll
        for (int ks = 0; ks < 4; ++ks) {
            u16x8 v;
#pragma unroll
            for (int j = 0; j < 8; ++j) {
                const int k = 32 * ks + 8 * lg + j;
                v[j] = f2bf(w2[k * 128 + colg]);
            }
            B2[ks][nt] = __builtin_bit_cast(bf16x8, v);
        }
    }
#pragma unroll
    for (int ks = 0; ks < 4; ++ks) {
        u16x8 v;
#pragma unroll
        for (int j = 0; j < 8; ++j) {
            const int k = 32 * ks + 8 * lg + j;
            v[j] = (l15 == 0) ? f2bf(aW[k]) : (l15 == 1 ? f2bf(pW2[k]) : (ushort_t)0);
        }
        Bg[ks] = __builtin_bit_cast(bf16x8, v);
    }

    const int ei = tid >> 2;   // edge slot 0..63 (staging)
    const int et = tid & 3;    // 4 threads per edge, each 32 floats per row

    for (int tile = blockIdx.x; tile < EE / 64; tile += gridDim.x) {
        __syncthreads();   // protect A/ROW/PD/GATE from previous iteration

        // ---- stage e_in tile (f32 -> bf16) ----
        {
            const int e = tile * 64 + ei;
            const int r = eidx[e];
            const int c = eidx[EE + e];
            const float* hr = h + (size_t)r * 128 + et * 32;
            const float* hc = h + (size_t)c * 128 + et * 32;
#pragma unroll
            for (int q = 0; q < 4; ++q) {
                u16x8 vr = cvt8(hr + q * 8);
                *reinterpret_cast<u16x8*>(&A_sh[ei * 296 + et * 32 + q * 8]) = vr;
                u16x8 vc = cvt8(hc + q * 8);
                *reinterpret_cast<u16x8*>(&A_sh[ei * 296 + 128 + et * 32 + q * 8]) = vc;
            }
            if (et == 0) {
                ROW_sh[ei] = r;
                const float dx = pos[r * 3 + 0] - pos[c * 3 + 0];
                const float dy = pos[r * 3 + 1] - pos[c * 3 + 1];
                const float dz = pos[r * 3 + 2] - pos[c * 3 + 2];
                PD_sh[ei][0] = dx; PD_sh[ei][1] = dy; PD_sh[ei][2] = dz;
                const float ds = dx * dx + dy * dy + dz * dz;
                u16x8 v0;
                v0[0] = f2bf(ds);
#pragma unroll
                for (int j = 0; j < 7; ++j) v0[1 + j] = f2bf(eattr[e * 8 + j]);
                *reinterpret_cast<u16x8*>(&A_sh[ei * 296 + 256]) = v0;
                u16x8 v1 = {0, 0, 0, 0, 0, 0, 0, 0};
                v1[0] = f2bf(eattr[e * 8 + 7]);
                *reinterpret_cast<u16x8*>(&A_sh[ei * 296 + 264]) = v1;
                u16x8 z = {0, 0, 0, 0, 0, 0, 0, 0};
                *reinterpret_cast<u16x8*>(&A_sh[ei * 296 + 272]) = z;
                *reinterpret_cast<u16x8*>(&A_sh[ei * 296 + 280]) = z;
            }
        }
        __syncthreads();

        // ---- layer 1: per subtile s, (16 x 288) @ (288 x 32-per-wave) ----
#pragma unroll
        for (int s = 0; s < 4; ++s) {
            f32x4 a0 = {0.f, 0.f, 0.f, 0.f};
            f32x4 a1 = {0.f, 0.f, 0.f, 0.f};
#pragma unroll
            for (int ks = 0; ks < 9; ++ks) {
                bf16x8 a = *reinterpret_cast<const bf16x8*>(
                    &A_sh[(16 * s + l15) * 296 + ks * 32 + lg * 8]);
                a0 = __builtin_amdgcn_mfma_f32_16x16x32_bf16(a, B1[ks][0], a0, 0, 0, 0);
                a1 = __builtin_amdgcn_mfma_f32_16x16x32_bf16(a, B1[ks][1], a1, 0, 0, 0);
            }
#pragma unroll
            for (int nt = 0; nt < 2; ++nt) {
#pragma unroll
                for (int rr = 0; rr < 4; ++rr) {
                    const float x = (nt == 0 ? a0[rr] : a1[rr]) + b1c[nt];
                    const int edge = 16 * s + 4 * lg + rr;
                    const int colg = 32 * w + 16 * nt + l15;
                    M1_sh[edge * 136 + colg] = f2bf(fsilu(x));
                }
            }
        }
        __syncthreads();   // M1 visible; all A reads done (M2 alias safe)

        // ---- layer 2 + M2 (ungated, bf16) stash ----
        float m2v[4][2][4];
#pragma unroll
        for (int s = 0; s < 4; ++s) {
            f32x4 a0 = {0.f, 0.f, 0.f, 0.f};
            f32x4 a1 = {0.f, 0.f, 0.f, 0.f};
#pragma unroll
            for (int ks = 0; ks < 4; ++ks) {
                bf16x8 a = *reinterpret_cast<const bf16x8*>(
                    &M1_sh[(16 * s + l15) * 136 + ks * 32 + lg * 8]);
                a0 = __builtin_amdgcn_mfma_f32_16x16x32_bf16(a, B2[ks][0], a0, 0, 0, 0);
                a1 = __builtin_amdgcn_mfma_f32_16x16x32_bf16(a, B2[ks][1], a1, 0, 0, 0);
            }
#pragma unroll
            for (int nt = 0; nt < 2; ++nt) {
#pragma unroll
                for (int rr = 0; rr < 4; ++rr) {
                    const float x = (nt == 0 ? a0[rr] : a1[rr]) + b2c[nt];
                    const float sv = fsilu(x);
                    m2v[s][nt][rr] = sv;
                    const int edge = 16 * s + 4 * lg + rr;
                    const int colg = 32 * w + 16 * nt + l15;
                    M2_sh[edge * 136 + colg] = f2bf(sv);
                }
            }
        }
        __syncthreads();   // M2 visible

        // ---- gate: wave w reduces subtile w via MFMA against [aW|pW2|0..] ----
        {
            f32x4 ga = {0.f, 0.f, 0.f, 0.f};
#pragma unroll
            for (int ks = 0; ks < 4; ++ks) {
                bf16x8 a = *reinterpret_cast<const bf16x8*>(
                    &M2_sh[(16 * w + l15) * 136 + ks * 32 + lg * 8]);
                ga = __builtin_amdgcn_mfma_f32_16x16x32_bf16(a, Bg[ks], ga, 0, 0, 0);
            }
            // l15==0 holds sa (raw), l15==1 holds sp, for edges 16w+4lg+rr
#pragma unroll
            for (int rr = 0; rr < 4; ++rr) {
                const float other = __shfl_xor(ga[rr], 1);
                if (l15 == 0) {
                    const int edge = 16 * w + 4 * lg + rr;
                    const float g = fsig(ga[rr] + abv);
                    const float t = g * other;
                    GATE_sh[edge] = g;
                    const int rw = ROW_sh[edge];
                    atomicAdd(&agg_t[rw * 3 + 0], PD_sh[edge][0] * t);
                    atomicAdd(&agg_t[rw * 3 + 1], PD_sh[edge][1] * t);
                    atomicAdd(&agg_t[rw * 3 + 2], PD_sh[edge][2] * t);
                    atomicAdd(&cnt[rw], 1.0f);
                }
            }
        }
        __syncthreads();   // GATE visible

        // ---- final: gated m write + agg scatter ----
#pragma unroll
        for (int s = 0; s < 4; ++s) {
#pragma unroll
            for (int nt = 0; nt < 2; ++nt) {
#pragma unroll
                for (int rr = 0; rr < 4; ++rr) {
                    const int edge = 16 * s + 4 * lg + rr;
                    const int colg = 32 * w + 16 * nt + l15;
                    const float mf = m2v[s][nt][rr] * GATE_sh[edge];
                    const size_t e = (size_t)tile * 64 + edge;
                    m_out[e * 128 + colg] = mf;
                    atomicAdd(&agg[(size_t)ROW_sh[edge] * 128 + colg], mf);
                }
            }
        }
    }
}

// ---------------------------------------------------------------------------
// Node kernel: h_new = silu([h | agg] @ nW1 + nb1) @ nW2 + nb2 + h
// ---------------------------------------------------------------------------
__global__ __launch_bounds__(256, 2) void egcl_node_kernel(
    const float* __restrict__ h, const float* __restrict__ agg,
    const float* __restrict__ w1, const float* __restrict__ b1,
    const float* __restrict__ w2, const float* __restrict__ b2,
    float* __restrict__ hn_out)
{
    __shared__ __align__(16) ushort_t A_sh[16 * 264];
    __shared__ __align__(16) ushort_t M1_sh[16 * 136];

    const int tid  = threadIdx.x;
    const int lane = tid & 63;
    const int w    = tid >> 6;
    const int l15  = lane & 15;
    const int lg   = lane >> 4;

    bf16x8 B1[8][2];
    bf16x8 B2[4][2];
    float b1c[2], b2c[2];
#pragma unroll
    for (int nt = 0; nt < 2; ++nt) {
        const int colg = 32 * w + 16 * nt + l15;
        b1c[nt] = b1[colg];
        b2c[nt] = b2[colg];
#pragma unroll
        for (int ks = 0; ks < 8; ++ks) {
            u16x8 v;
#pragma unroll
            for (int j = 0; j < 8; ++j) {
                const int k = 32 * ks + 8 * lg + j;
                v[j] = f2bf(w1[k * 128 + colg]);
            }
            B1[ks][nt] = __builtin_bit_cast(bf16x8, v);
        }
#pragma unroll
        for (int ks = 0; ks < 4; ++ks) {
            u16x8 v;
#pragma unroll
            for (int j = 0; j < 8; ++j) {
                const int k = 32 * ks + 8 * lg + j;
                v[j] = f2bf(w2[k * 128 + colg]);
            }
            B2[ks][nt] = __builtin_bit_cast(bf16x8, v);
        }
    }

    const int ni = tid >> 4;
    const int nt16 = tid & 15;

    for (int tile = blockIdx.x; tile < NN / 16; tile += gridDim.x) {
        __syncthreads();
        {
            const size_t n = (size_t)tile * 16 + ni;
            u16x8 hv = cvt8(h + n * 128 + nt16 * 8);
            *reinterpret_cast<u16x8*>(&A_sh[ni * 264 + nt16 * 8]) = hv;
            u16x8 av = cvt8(agg + n * 128 + nt16 * 8);
            *reinterpret_cast<u16x8*>(&A_sh[ni * 264 + 128 + nt16 * 8]) = av;
        }
        __syncthreads();

        f32x4 acc10 = {0.f, 0.f, 0.f, 0.f};
        f32x4 acc11 = {0.f, 0.f, 0.f, 0.f};
#pragma unroll
        for (int ks = 0; ks < 8; ++ks) {
            bf16x8 a = *reinterpret_cast<const bf16x8*>(&A_sh[l15 * 264 + ks * 32 + lg * 8]);
            acc10 = __builtin_amdgcn_mfma_f32_16x16x32_bf16(a, B1[ks][0], acc10, 0, 0, 0);
            acc11 = __builtin_amdgcn_mfma_f32_16x16x32_bf16(a, B1[ks][1], acc11, 0, 0, 0);
        }
#pragma unroll
        for (int nt = 0; nt < 2; ++nt) {
#pragma unroll
            for (int r = 0; r < 4; ++r) {
                const float x = (nt == 0 ? acc10[r] : acc11[r]) + b1c[nt];
                const int nl = 4 * lg + r;
                const int colg = 32 * w + 16 * nt + l15;
                M1_sh[nl * 136 + colg] = f2bf(fsilu(x));
            }
        }
        __syncthreads();

        f32x4 acc20 = {0.f, 0.f, 0.f, 0.f};
        f32x4 acc21 = {0.f, 0.f, 0.f, 0.f};
#pragma unroll
        for (int ks = 0; ks < 4; ++ks) {
            bf16x8 a = *reinterpret_cast<const bf16x8*>(&M1_sh[l15 * 136 + ks * 32 + lg * 8]);
            acc20 = __builtin_amdgcn_mfma_f32_16x16x32_bf16(a, B2[ks][0], acc20, 0, 0, 0);
            acc21 = __builtin_amdgcn_mfma_f32_16x16x32_bf16(a, B2[ks][1], acc21, 0, 0, 0);
        }
#pragma unroll
        for (int nt = 0; nt < 2; ++nt) {
#pragma unroll
            for (int r = 0; r < 4; ++r) {
                const int nl = 4 * lg + r;
                const int colg = 32 * w + 16 * nt + l15;
                const size_t n = (size_t)tile * 16 + nl;
                const float hres = h[n * 128 + colg];
                const float y = (nt == 0 ? acc20[r] : acc21[r]) + b2c[nt] + hres;
                hn_out[n * 128 + colg] = y;
            }
        }
    }
}

__global__ void egcl_pos_kernel(const float* __restrict__ pos,
                               const float* __restrict__ agg_t,
                               const float* __restrict__ cnt,
                               float* __restrict__ pos_out)
{
    const int n = blockIdx.x * 256 + threadIdx.x;
    if (n < NN) {
        const float c = fmaxf(cnt[n], 1.0f);
#pragma unroll
        for (int d = 0; d < 3; ++d) {
            pos_out[n * 3 + d] = pos[n * 3 + d] + agg_t[n * 3 + d] / c;
        }
    }
}

extern "C" void kernel_launch(void* const* d_in, const int* in_sizes, int n_in,
                              void* d_out, int out_size, void* d_ws, size_t ws_size,
                              hipStream_t stream)
{
    const float* h     = (const float*)d_in[0];
    const float* pos   = (const float*)d_in[1];
    const int*   eidx  = (const int*)d_in[2];
    const float* eattr = (const float*)d_in[3];
    const float* eW1   = (const float*)d_in[4];
    const float* eb1   = (const float*)d_in[5];
    const float* eW2   = (const float*)d_in[6];
    const float* eb2   = (const float*)d_in[7];
    const float* aW    = (const float*)d_in[8];
    const float* ab    = (const float*)d_in[9];
    const float* nW1   = (const float*)d_in[10];
    const float* nb1   = (const float*)d_in[11];
    const float* nW2   = (const float*)d_in[12];
    const float* nb2   = (const float*)d_in[13];
    const float* pW2   = (const float*)d_in[14];

    float* out    = (float*)d_out;
    float* hn_out = out;                                   // N*128
    float* po_out = out + (size_t)NN * 128;                // N*3
    float* m_out  = po_out + (size_t)NN * 3;               // E*128

    float* agg   = (float*)d_ws;                           // N*128 f32
    float* agg_t = agg + (size_t)NN * 128;                 // N*3
    float* cnt   = agg_t + (size_t)NN * 3;                 // N

    const size_t zbytes = sizeof(float) * (size_t)NN * (128 + 3 + 1);
    hipMemsetAsync(d_ws, 0, zbytes, stream);

    egcl_edge_kernel<<<512, 256, 0, stream>>>(h, pos, eidx, eattr,
                                              eW1, eb1, eW2, eb2, aW, ab, pW2,
                                              m_out, agg, agg_t, cnt);
    egcl_node_kernel<<<512, 256, 0, stream>>>(h, agg, nW1, nb1, nW2, nb2, hn_out);
    egcl_pos_kernel<<<(NN + 255) / 256, 256, 0, stream>>>(pos, agg_t, cnt, po_out);
}